// Round 6
// baseline (521.136 us; speedup 1.0000x reference)
//
#include <hip/hip_runtime.h>

#define N_NODES   100000
#define N_EDGES   1600000
#define NFEAT     128
#define N_GRAPHS  1024

#define NBUCK   391                  // ceil(100000 / 256) — scan granularity
#define SC_EDGES 4096
#define SC_EPT   8                   // edges per thread (4096/512)
#define SC_BLOCKS 391                // ceil(1.6M / 4096)

#define WT_STRIDE 136
#define GEMM_BLOCKS 782              // ceil(100000/128)

typedef unsigned int uint32;
typedef unsigned short ushort;
typedef __attribute__((ext_vector_type(8))) short short8;   // 8 bf16 (4 VGPRs)
typedef __attribute__((ext_vector_type(4))) float f32x4;

// fp32 -> bf16 bits, round-to-nearest-even (finite inputs)
__device__ inline ushort f2b(float f) {
    uint32 x = __float_as_uint(f);
    uint32 r = x + 0x7fffu + ((x >> 16) & 1u);
    return (ushort)(r >> 16);
}
__device__ inline float blo(uint32 u) { return __uint_as_float(u << 16); }
__device__ inline float bhi(uint32 u) { return __uint_as_float(u & 0xffff0000u); }

__device__ inline short8 cvt8(const float* p) {
    float4 v0 = ((const float4*)p)[0];
    float4 v1 = ((const float4*)p)[1];
    short8 r;
    r[0] = (short)f2b(v0.x); r[1] = (short)f2b(v0.y);
    r[2] = (short)f2b(v0.z); r[3] = (short)f2b(v0.w);
    r[4] = (short)f2b(v1.x); r[5] = (short)f2b(v1.y);
    r[6] = (short)f2b(v1.z); r[7] = (short)f2b(v1.w);
    return r;
}

// ---------------- cast+transpose W -> WT bf16 [layer][n][k]; also zero deg ----------------
__global__ __launch_bounds__(256) void k_castw(const float* __restrict__ W1, const float* __restrict__ W2,
                                               const float* __restrict__ W3, ushort* __restrict__ WT,
                                               int* __restrict__ deg) {
    int i = blockIdx.x * blockDim.x + threadIdx.x;   // 391*256 = 100096 threads
    if (i < N_NODES) deg[i] = 0;
    if (i >= 3 * NFEAT * NFEAT) return;
    int l = i >> 14;
    int j = i & 16383;
    int n = j >> 7;
    int k = j & 127;
    const float* W = (l == 0) ? W1 : (l == 1) ? W2 : W3;
    WT[i] = f2b(W[k * NFEAT + n]);   // WT[l][n*128+k] = W[k][n]
}

// ---------------- phase 1: degree histogram (blocks 0..390) || layer-1 GEMM (391..1172) ----------------
__global__ __launch_bounds__(512) void k_phase1(const int* __restrict__ src, const int* __restrict__ dst,
                                                int* __restrict__ deg,
                                                const float* __restrict__ A, const ushort* __restrict__ WTl,
                                                ushort* __restrict__ C, int M) {
    __shared__ __align__(16) ushort sWT[NFEAT * WT_STRIDE];   // 34 KB (GEMM branch only)
    int t = threadIdx.x;
    if (blockIdx.x < SC_BLOCKS) {
        // ================== degree histogram: fire-and-forget global atomics ==================
        int e0 = blockIdx.x * SC_EDGES;
        #pragma unroll
        for (int k = 0; k < SC_EPT; ++k) {
            int i = e0 + t + k * 512;
            if (i < N_EDGES) atomicAdd(&deg[dst[i]], 1);
        }
    } else {
        // ================== layer-1 GEMM (fp32 A, cast fused) ==================
        int gb = blockIdx.x - SC_BLOCKS;
        for (int i = t; i < NFEAT * 16; i += 512) {
            int n = i >> 4, c = i & 15;
            *(float4*)(sWT + n * WT_STRIDE + c * 8) = ((const float4*)WTl)[i];
        }
        int wave = t >> 6, lane = t & 63;
        int m0 = gb * 128 + wave * 16;
        int mRow = m0 + (lane & 15);
        if (mRow >= M) mRow = M - 1;
        int kg = lane >> 4;
        const float* Ap = A + (size_t)mRow * NFEAT + kg * 8;
        short8 a0 = cvt8(Ap);
        short8 a1 = cvt8(Ap + 32);
        short8 a2 = cvt8(Ap + 64);
        short8 a3 = cvt8(Ap + 96);
        __syncthreads();

        f32x4 acc[8];
        #pragma unroll
        for (int nt = 0; nt < 8; ++nt) acc[nt] = (f32x4){0.f, 0.f, 0.f, 0.f};
        #pragma unroll
        for (int nt = 0; nt < 8; ++nt) {
            int n = nt * 16 + (lane & 15);
            const short8* Bp = (const short8*)(sWT + n * WT_STRIDE + kg * 8);
            short8 b0 = Bp[0];
            short8 b1 = Bp[4];
            short8 b2 = Bp[8];
            short8 b3 = Bp[12];
            acc[nt] = __builtin_amdgcn_mfma_f32_16x16x32_bf16(a0, b0, acc[nt], 0, 0, 0);
            acc[nt] = __builtin_amdgcn_mfma_f32_16x16x32_bf16(a1, b1, acc[nt], 0, 0, 0);
            acc[nt] = __builtin_amdgcn_mfma_f32_16x16x32_bf16(a2, b2, acc[nt], 0, 0, 0);
            acc[nt] = __builtin_amdgcn_mfma_f32_16x16x32_bf16(a3, b3, acc[nt], 0, 0, 0);
        }
        __syncthreads();
        {
            int colBase = lane & 15;
            #pragma unroll
            for (int r = 0; r < 4; ++r) {
                int lr = wave * 16 + kg * 4 + r;
                #pragma unroll
                for (int nt = 0; nt < 8; ++nt)
                    sWT[lr * NFEAT + nt * 16 + colBase] = f2b(acc[nt][r]);
            }
        }
        __syncthreads();
        {
            int rowBase = gb * 128;
            const float4* sC4 = (const float4*)sWT;
            for (int i = t; i < 2048; i += 512) {
                int row = i >> 4;
                int gr = rowBase + row;
                if (gr < M) ((float4*)(C + (size_t)gr * NFEAT))[i & 15] = sC4[i];
            }
        }
    }
}

// ---------------- scan stage 1: per-256-node block sums ----------------
__global__ __launch_bounds__(256) void k_scan1(const int* __restrict__ deg, int* __restrict__ bsum) {
    int node = blockIdx.x * 256 + threadIdx.x;
    int d = (node < N_NODES) ? deg[node] : 0;
    int lane = threadIdx.x & 63, w = threadIdx.x >> 6;
    #pragma unroll
    for (int s = 32; s > 0; s >>= 1) d += __shfl_down(d, s, 64);
    __shared__ int ws[4];
    if (lane == 0) ws[w] = d;
    __syncthreads();
    if (threadIdx.x == 0) bsum[blockIdx.x] = ws[0] + ws[1] + ws[2] + ws[3];
}

// ---------------- scan stage 2: offsets / cursor / dinv (redundant 391-scan per block) ----------------
__global__ __launch_bounds__(256) void k_scan2(const int* __restrict__ deg, const int* __restrict__ bsum,
                                               int* __restrict__ offsets, int* __restrict__ cursor,
                                               float* __restrict__ dinv) {
    int b = blockIdx.x, t = threadIdx.x;
    __shared__ int wsum[4], wtot[4];
    __shared__ int sBase, sTotal;
    int lane = t & 63, w = t >> 6;
    {
        int pre = 0, tot = 0;
        #pragma unroll
        for (int q = 0; q < 2; ++q) {
            int i = 2 * t + q;
            if (i < NBUCK) {
                int v = bsum[i];
                tot += v;
                if (i < b) pre += v;
            }
        }
        #pragma unroll
        for (int s = 32; s > 0; s >>= 1) { pre += __shfl_down(pre, s, 64); tot += __shfl_down(tot, s, 64); }
        if (lane == 0) { wsum[w] = pre; wtot[w] = tot; }
        __syncthreads();
        if (t == 0) {
            sBase = wsum[0] + wsum[1] + wsum[2] + wsum[3];
            sTotal = wtot[0] + wtot[1] + wtot[2] + wtot[3];
        }
    }
    __syncthreads();
    int node = (b << 8) + t;
    int c = (node < N_NODES) ? deg[node] : 0;
    // block-local exclusive scan of c
    int inc = c;
    #pragma unroll
    for (int d2 = 1; d2 < 64; d2 <<= 1) {
        int u = __shfl_up(inc, d2, 64);
        if (lane >= d2) inc += u;
    }
    if (lane == 63) wsum[w] = inc;
    __syncthreads();
    int wpre = 0;
    for (int i = 0; i < w; ++i) wpre += wsum[i];
    int e = sBase + wpre + inc - c;
    if (node < N_NODES) {
        offsets[node] = e;
        cursor[node]  = e;
        dinv[node] = rsqrtf((float)(c + 1));
    }
    if (b == NBUCK - 1 && t == 0) offsets[N_NODES] = sTotal;
}

// ---------------- scatter: ticketed fill of CSR col (order within node irrelevant) ----------------
__global__ __launch_bounds__(512) void k_scatter(const int* __restrict__ src, const int* __restrict__ dst,
                                                 int* __restrict__ cursor, int* __restrict__ col) {
    int base = blockIdx.x * 2048;
    #pragma unroll
    for (int k = 0; k < 4; ++k) {
        int i = base + k * 512 + threadIdx.x;
        if (i < N_EDGES) {
            int d = dst[i];
            int pos = atomicAdd(&cursor[d], 1);
            col[pos] = src[i];
        }
    }
}

// ---------------- aggregation core: 4 nodes per wave, 8-wide gather pipeline ----------------
#define AGG_GROUP4 \
    int half = lane >> 4; \
    int fl = lane & 15; \
    float dn = dinv[n]; \
    int e0 = off[n], e1 = off[n + 1]; \
    int deg = e1 - e0; \
    int maxd = deg; \
    { int u16 = __shfl_xor(maxd, 16, 64); if (u16 > maxd) maxd = u16; \
      int u32 = __shfl_xor(maxd, 32, 64); if (u32 > maxd) maxd = u32; } \
    const uint4* XW4 = (const uint4*)XWu; \
    uint4 sv = XW4[(size_t)n * 16 + fl]; \
    float ws = dn * dn; \
    float a0 = ws * blo(sv.x), a1 = ws * bhi(sv.x); \
    float a2 = ws * blo(sv.y), a3 = ws * bhi(sv.y); \
    float a4 = ws * blo(sv.z), a5 = ws * bhi(sv.z); \
    float a6 = ws * blo(sv.w), a7 = ws * bhi(sv.w); \
    int cm = 0; float wm = 0.f; \
    if (fl < deg) { cm = col[e0 + fl]; wm = dn * dinv[cm]; } \
    for (int base = 0; base < maxd; base += 16) { \
        int nb = base + 16; \
        int cmn = 0; float wmn = 0.f; \
        if (nb + fl < deg) { cmn = col[e0 + nb + fl]; wmn = dn * dinv[cmn]; } \
        int lim = maxd - base; if (lim > 16) lim = 16; \
        for (int j = 0; j < lim; j += 8) { \
            uint4 u[8]; float w[8]; \
            _Pragma("unroll") \
            for (int p = 0; p < 8; ++p) { \
                int sl = (half << 4) + j + p; \
                int cc = __shfl(cm, sl, 64); \
                w[p] = __shfl(wm, sl, 64); \
                u[p] = XW4[(size_t)cc * 16 + fl]; \
            } \
            _Pragma("unroll") \
            for (int p = 0; p < 8; ++p) { \
                a0 = fmaf(w[p], blo(u[p].x), a0); a1 = fmaf(w[p], bhi(u[p].x), a1); \
                a2 = fmaf(w[p], blo(u[p].y), a2); a3 = fmaf(w[p], bhi(u[p].y), a3); \
                a4 = fmaf(w[p], blo(u[p].z), a4); a5 = fmaf(w[p], bhi(u[p].z), a5); \
                a6 = fmaf(w[p], blo(u[p].w), a6); a7 = fmaf(w[p], bhi(u[p].w), a7); \
            } \
        } \
        cm = cmn; wm = wmn; \
    }

// ---------------- fused: agg(+bias,relu) 16 nodes/block -> 4.3KB LDS A-tile -> MFMA @ W ----------------
__global__ __launch_bounds__(256) void k_agg_gemm(const uint32* __restrict__ XWu,
                                                  const int* __restrict__ col,
                                                  const int* __restrict__ off,
                                                  const float* __restrict__ dinv,
                                                  const float* __restrict__ bias,
                                                  const ushort* __restrict__ WTl,
                                                  ushort* __restrict__ C) {
    __shared__ __align__(16) ushort sA[16 * WT_STRIDE];   // 4.25 KB (A-tile, reused for C staging)
    int t = threadIdx.x;
    int lane = t & 63;
    int lw = t >> 6;                                      // wave 0..3
    int n = (blockIdx.x << 4) + (lw << 2) + (lane >> 4);  // N_NODES = 6250*16 exactly, no tail
    AGG_GROUP4
    // bias + relu + pack to bf16, stage row into LDS
    {
        float4 bb0 = ((const float4*)bias)[2 * fl];
        float4 bb1 = ((const float4*)bias)[2 * fl + 1];
        float r0 = fmaxf(a0 + bb0.x, 0.f), r1 = fmaxf(a1 + bb0.y, 0.f);
        float r2 = fmaxf(a2 + bb0.z, 0.f), r3 = fmaxf(a3 + bb0.w, 0.f);
        float r4 = fmaxf(a4 + bb1.x, 0.f), r5 = fmaxf(a5 + bb1.y, 0.f);
        float r6 = fmaxf(a6 + bb1.z, 0.f), r7 = fmaxf(a7 + bb1.w, 0.f);
        uint4 o;
        o.x = (uint32)f2b(r0) | ((uint32)f2b(r1) << 16);
        o.y = (uint32)f2b(r2) | ((uint32)f2b(r3) << 16);
        o.z = (uint32)f2b(r4) | ((uint32)f2b(r5) << 16);
        o.w = (uint32)f2b(r6) | ((uint32)f2b(r7) << 16);
        int lrow = (lw << 2) + half;                      // local node 0..15
        *(uint4*)(sA + lrow * WT_STRIDE + fl * 8) = o;
    }
    __syncthreads();
    // GEMM epilogue: wave lw computes column-tiles nt = 2lw, 2lw+1 of C[16,128]
    {
        const short8* Ap = (const short8*)(sA + fl * WT_STRIDE + half * 8);
        short8 af0 = Ap[0];
        short8 af1 = Ap[4];
        short8 af2 = Ap[8];
        short8 af3 = Ap[12];
        f32x4 acc[2];
        acc[0] = (f32x4){0.f, 0.f, 0.f, 0.f};
        acc[1] = (f32x4){0.f, 0.f, 0.f, 0.f};
        #pragma unroll
        for (int q = 0; q < 2; ++q) {
            int nt = lw * 2 + q;
            const short8* Bp = (const short8*)(WTl + (nt * 16 + fl) * NFEAT + half * 8);
            short8 b0 = Bp[0];
            short8 b1 = Bp[4];
            short8 b2 = Bp[8];
            short8 b3 = Bp[12];
            acc[q] = __builtin_amdgcn_mfma_f32_16x16x32_bf16(af0, b0, acc[q], 0, 0, 0);
            acc[q] = __builtin_amdgcn_mfma_f32_16x16x32_bf16(af1, b1, acc[q], 0, 0, 0);
            acc[q] = __builtin_amdgcn_mfma_f32_16x16x32_bf16(af2, b2, acc[q], 0, 0, 0);
            acc[q] = __builtin_amdgcn_mfma_f32_16x16x32_bf16(af3, b3, acc[q], 0, 0, 0);
        }
        __syncthreads();
        // C/D layout: col = lane&15 (fl), row = (lane>>4)*4 + r (half*4+r)
        #pragma unroll
        for (int q = 0; q < 2; ++q) {
            int nt = lw * 2 + q;
            #pragma unroll
            for (int r = 0; r < 4; ++r)
                sA[(half * 4 + r) * NFEAT + nt * 16 + fl] = f2b(acc[q][r]);
        }
    }
    __syncthreads();
    {
        int row = t >> 4;                                 // 0..15
        float4 v = ((const float4*)sA)[t];                // 256 float4 = 16 rows x 128 ushort
        ((float4*)(C + (size_t)((blockIdx.x << 4) + row) * NFEAT))[t & 15] = v;
    }
}

__global__ __launch_bounds__(256) void k_agg_fc(const uint32* __restrict__ XWu, const int* __restrict__ col,
                                                const int* __restrict__ off, const float* __restrict__ dinv,
                                                const float* __restrict__ bias, const float* __restrict__ Wfc,
                                                float* __restrict__ nodeS) {
    int wid = (blockIdx.x * blockDim.x + threadIdx.x) >> 6;
    int lane = threadIdx.x & 63;
    int n = (wid << 2) + (lane >> 4);
    if (n >= N_NODES) return;
    AGG_GROUP4
    float4 bb0 = ((const float4*)bias)[2 * fl];
    float4 bb1 = ((const float4*)bias)[2 * fl + 1];
    float4 wf0 = ((const float4*)Wfc)[2 * fl];
    float4 wf1 = ((const float4*)Wfc)[2 * fl + 1];
    float s = fmaxf(a0 + bb0.x, 0.f) * wf0.x + fmaxf(a1 + bb0.y, 0.f) * wf0.y
            + fmaxf(a2 + bb0.z, 0.f) * wf0.z + fmaxf(a3 + bb0.w, 0.f) * wf0.w
            + fmaxf(a4 + bb1.x, 0.f) * wf1.x + fmaxf(a5 + bb1.y, 0.f) * wf1.y
            + fmaxf(a6 + bb1.z, 0.f) * wf1.z + fmaxf(a7 + bb1.w, 0.f) * wf1.w;
    // reduce within the 16-lane group (xor distances 8/4/2/1 stay inside the group)
    s += __shfl_xor(s, 8, 64);
    s += __shfl_xor(s, 4, 64);
    s += __shfl_xor(s, 2, 64);
    s += __shfl_xor(s, 1, 64);
    if (fl == 0) nodeS[n] = s;
}

// ---------------- segment mean over sorted batch + bias (one block per graph) ----------------
__device__ inline int lower_bound_dev(const int* a, int n, int key) {
    int lo = 0, hi = n;
    while (lo < hi) {
        int mid = (lo + hi) >> 1;
        if (a[mid] < key) lo = mid + 1; else hi = mid;
    }
    return lo;
}

__global__ __launch_bounds__(256) void k_pool(const float* __restrict__ nodeS, const int* __restrict__ batch,
                                              const float* __restrict__ bfc, float* __restrict__ out) {
    int g = blockIdx.x;
    int t = threadIdx.x;
    int lo = lower_bound_dev(batch, N_NODES, g);
    int hi = lower_bound_dev(batch, N_NODES, g + 1);
    float s = 0.f;
    for (int i = lo + t; i < hi; i += 256) s += nodeS[i];
    for (int d = 32; d > 0; d >>= 1) s += __shfl_down(s, d, 64);
    __shared__ float ws[4];
    int lane = t & 63, w = t >> 6;
    if (lane == 0) ws[w] = s;
    __syncthreads();
    if (t == 0) {
        float tot = ws[0] + ws[1] + ws[2] + ws[3];
        float cnt = (float)(hi - lo);
        out[g] = tot / fmaxf(cnt, 1.0f) + bfc[0];
    }
}

// ---------------- launch ----------------
extern "C" void kernel_launch(void* const* d_in, const int* in_sizes, int n_in,
                              void* d_out, int out_size, void* d_ws, size_t ws_size,
                              hipStream_t stream) {
    const float* x    = (const float*)d_in[0];
    const int*   ei   = (const int*)d_in[1];     // [2, E] : row0 = src, row1 = dst
    const int*   batch= (const int*)d_in[2];
    const float* W1   = (const float*)d_in[3];
    const float* b1   = (const float*)d_in[4];
    const float* W2   = (const float*)d_in[5];
    const float* b2   = (const float*)d_in[6];
    const float* W3   = (const float*)d_in[7];
    const float* b3   = (const float*)d_in[8];
    const float* Wfc  = (const float*)d_in[9];
    const float* bfc  = (const float*)d_in[10];
    float* out = (float*)d_out;

    const int* src = ei;
    const int* dst = ei + N_EDGES;

    // carve workspace (256B-aligned)
    char* p = (char*)d_ws;
    auto carve = [&](size_t bytes) { void* r = (void*)p; p += (bytes + 255) & ~(size_t)255; return r; };
    int*    deg       = (int*)   carve(sizeof(int) * N_NODES);
    int*    bsum      = (int*)   carve(sizeof(int) * NBUCK);
    int*    cursor    = (int*)   carve(sizeof(int) * N_NODES);
    float*  dinv      = (float*) carve(sizeof(float) * N_NODES);
    int*    offsets   = (int*)   carve(sizeof(int) * (N_NODES + 1));
    int*    col       = (int*)   carve(sizeof(int) * N_EDGES);
    ushort* XW        = (ushort*)carve(sizeof(short) * (size_t)N_NODES * NFEAT);
    ushort* XW2       = (ushort*)carve(sizeof(short) * (size_t)N_NODES * NFEAT);          // ping-pong
    ushort* WT        = (ushort*)carve(sizeof(short) * 3 * NFEAT * NFEAT);
    float*  nodeS     = (float*) carve(sizeof(float) * N_NODES);

    const int aggBlocks = N_NODES / 16;   // 6250 exactly (100000 = 6250*16)

    k_castw<<<NBUCK, 256, 0, stream>>>(W1, W2, W3, WT, deg);
    // phase 1: degree histogram || layer-1 GEMM (independent work co-scheduled)  -> XW = x @ W1
    k_phase1<<<SC_BLOCKS + GEMM_BLOCKS, 512, 0, stream>>>(src, dst, deg, x, WT, XW, N_NODES);
    k_scan1<<<NBUCK, 256, 0, stream>>>(deg, bsum);
    k_scan2<<<NBUCK, 256, 0, stream>>>(deg, bsum, offsets, cursor, dinv);
    k_scatter<<<GEMM_BLOCKS, 512, 0, stream>>>(src, dst, cursor, col);

    // fused layer-1 agg + layer-2 GEMM:  XW2 = relu(A·XW + b1) @ W2
    k_agg_gemm<<<aggBlocks, 256, 0, stream>>>((const uint32*)XW, col, offsets, dinv, b1,
                                              WT + NFEAT * NFEAT, XW2);
    // fused layer-2 agg + layer-3 GEMM:  XW = relu(A·XW2 + b2) @ W3
    k_agg_gemm<<<aggBlocks, 256, 0, stream>>>((const uint32*)XW2, col, offsets, dinv, b2,
                                              WT + 2 * NFEAT * NFEAT, XW);
    // layer-3 agg + FC
    k_agg_fc<<<aggBlocks, 256, 0, stream>>>((const uint32*)XW, col, offsets, dinv, b3, Wfc, nodeS);

    k_pool<<<N_GRAPHS, 256, 0, stream>>>(nodeS, batch, bfc, out);
}

// Round 7
// 514.155 us; speedup vs baseline: 1.0136x; 1.0136x over previous
//
#include <hip/hip_runtime.h>

#define N_NODES   100000
#define N_EDGES   1600000
#define NFEAT     128
#define N_GRAPHS  1024

// ---- bucketed CSR build ----
#define BSHIFT  8
#define BNODES  256
#define NBUCK   391                  // ceil(100000 / 256)
#define BCAP    4608                 // mean 4096 + 8 sigma
#define SC_EDGES 4096
#define SC_EPT   8                   // edges per thread (4096/512)
#define SC_BLOCKS 391                // ceil(1.6M / 4096)
#define BD_EPT   18                  // ceil(BCAP/256)

#define WT_STRIDE 136
#define GEMM_BLOCKS 782              // ceil(100000/128)

typedef unsigned int uint32;
typedef unsigned short ushort;
typedef __attribute__((ext_vector_type(8))) short short8;   // 8 bf16 (4 VGPRs)
typedef __attribute__((ext_vector_type(4))) float f32x4;

// fp32 -> bf16 bits, round-to-nearest-even (finite inputs)
__device__ inline ushort f2b(float f) {
    uint32 x = __float_as_uint(f);
    uint32 r = x + 0x7fffu + ((x >> 16) & 1u);
    return (ushort)(r >> 16);
}
__device__ inline float blo(uint32 u) { return __uint_as_float(u << 16); }
__device__ inline float bhi(uint32 u) { return __uint_as_float(u & 0xffff0000u); }

__device__ inline short8 cvt8(const float* p) {
    float4 v0 = ((const float4*)p)[0];
    float4 v1 = ((const float4*)p)[1];
    short8 r;
    r[0] = (short)f2b(v0.x); r[1] = (short)f2b(v0.y);
    r[2] = (short)f2b(v0.z); r[3] = (short)f2b(v0.w);
    r[4] = (short)f2b(v1.x); r[5] = (short)f2b(v1.y);
    r[6] = (short)f2b(v1.z); r[7] = (short)f2b(v1.w);
    return r;
}

// ---------------- cast+transpose W -> WT bf16 [layer][n][k]; also zero cur ----------------
__global__ __launch_bounds__(256) void k_castw(const float* __restrict__ W1, const float* __restrict__ W2,
                                               const float* __restrict__ W3, ushort* __restrict__ WT,
                                               int* __restrict__ cur) {
    int i = blockIdx.x * blockDim.x + threadIdx.x;   // 3*16384
    if (i < NBUCK) cur[i] = 0;
    if (i >= 3 * NFEAT * NFEAT) return;
    int l = i >> 14;
    int j = i & 16383;
    int n = j >> 7;
    int k = j & 127;
    const float* W = (l == 0) ? W1 : (l == 1) ? W2 : W3;
    WT[i] = f2b(W[k * NFEAT + n]);   // WT[l][n*128+k] = W[k][n]
}

// ---------------- phase 1: scatter (blocks 0..390) || layer-1 GEMM (blocks 391..1172) ----------------
struct SMemScatter {
    int hist[NBUCK], lofs[NBUCK], gbase[NBUCK];
    int wsum[4];
    uint32 sortedP[SC_EDGES];   // 16 KB
    ushort sortedB[SC_EDGES];   //  8 KB
};

__global__ __launch_bounds__(512) void k_phase1(const int* __restrict__ src, const int* __restrict__ dst,
                                                int* __restrict__ cur, uint32* __restrict__ bbuf,
                                                const float* __restrict__ A, const ushort* __restrict__ WTl,
                                                ushort* __restrict__ C, int M) {
    __shared__ __align__(16) char smem[NFEAT * WT_STRIDE * 2];   // 34 KB >= sizeof(SMemScatter)
    int t = threadIdx.x;
    if (blockIdx.x < SC_BLOCKS) {
        // ================== scatter: single-pass ticketed counting sort ==================
        SMemScatter& S = *(SMemScatter*)smem;
        int e0 = blockIdx.x * SC_EDGES;
        int total = N_EDGES - e0; if (total > SC_EDGES) total = SC_EDGES; if (total < 0) total = 0;
        for (int i = t; i < NBUCK; i += 512) S.hist[i] = 0;
        __syncthreads();
        uint32 val[SC_EPT];
        int    meta[SC_EPT];    // (bucket << 13) | ticket
        #pragma unroll
        for (int k = 0; k < SC_EPT; ++k) {
            int i = t + k * 512;
            meta[k] = -1;
            if (i < total) {
                int s = src[e0 + i], d = dst[e0 + i];
                int b = d >> BSHIFT;
                int tk = atomicAdd(&S.hist[b], 1);
                val[k] = ((uint32)(d & (BNODES - 1)) << 17) | (uint32)s;
                meta[k] = (b << 13) | tk;
            }
        }
        __syncthreads();
        // scan of 391 bins on first 256 threads (2/thread) + per-bin global reservation
        int inc = 0, ts = 0, h0 = 0;
        if (t < 256) {
            int b0 = 2 * t, b1 = 2 * t + 1;
            h0 = (b0 < NBUCK) ? S.hist[b0] : 0;
            int h1 = (b1 < NBUCK) ? S.hist[b1] : 0;
            ts = h0 + h1;
            int lane = t & 63;
            inc = ts;
            #pragma unroll
            for (int d = 1; d < 64; d <<= 1) {
                int u = __shfl_up(inc, d, 64);
                if (lane >= d) inc += u;
            }
            if (lane == 63) S.wsum[t >> 6] = inc;
        }
        __syncthreads();
        if (t < 256) {
            int w = t >> 6;
            int wpre = 0;
            for (int i = 0; i < w; ++i) wpre += S.wsum[i];
            int run = wpre + inc - ts;
            int b0 = 2 * t, b1 = 2 * t + 1;
            int h1 = ts - h0;
            if (b0 < NBUCK) {
                S.lofs[b0] = run;
                if (h0) S.gbase[b0] = atomicAdd(&cur[b0], h0);
            }
            if (b1 < NBUCK) {
                S.lofs[b1] = run + h0;
                if (h1) S.gbase[b1] = atomicAdd(&cur[b1], h1);
            }
        }
        __syncthreads();
        #pragma unroll
        for (int k = 0; k < SC_EPT; ++k) {
            if (meta[k] >= 0) {
                int b = meta[k] >> 13;
                int p = S.lofs[b] + (meta[k] & 0x1FFF);
                S.sortedP[p] = val[k];
                S.sortedB[p] = (ushort)b;
            }
        }
        __syncthreads();
        for (int i = t; i < total; i += 512) {
            int b = S.sortedB[i];
            int addr = S.gbase[b] + (i - S.lofs[b]);
            if (addr < BCAP)
                bbuf[(size_t)b * BCAP + addr] = S.sortedP[i];
        }
    } else {
        // ================== layer-1 GEMM (fp32 A, cast fused) ==================
        ushort* sWT = (ushort*)smem;
        int gb = blockIdx.x - SC_BLOCKS;
        for (int i = t; i < NFEAT * 16; i += 512) {
            int n = i >> 4, c = i & 15;
            *(float4*)(sWT + n * WT_STRIDE + c * 8) = ((const float4*)WTl)[i];
        }
        int wave = t >> 6, lane = t & 63;
        int m0 = gb * 128 + wave * 16;
        int mRow = m0 + (lane & 15);
        if (mRow >= M) mRow = M - 1;
        int kg = lane >> 4;
        const float* Ap = A + (size_t)mRow * NFEAT + kg * 8;
        short8 a0 = cvt8(Ap);
        short8 a1 = cvt8(Ap + 32);
        short8 a2 = cvt8(Ap + 64);
        short8 a3 = cvt8(Ap + 96);
        __syncthreads();

        f32x4 acc[8];
        #pragma unroll
        for (int nt = 0; nt < 8; ++nt) acc[nt] = (f32x4){0.f, 0.f, 0.f, 0.f};
        #pragma unroll
        for (int nt = 0; nt < 8; ++nt) {
            int n = nt * 16 + (lane & 15);
            const short8* Bp = (const short8*)(sWT + n * WT_STRIDE + kg * 8);
            short8 b0 = Bp[0];
            short8 b1 = Bp[4];
            short8 b2 = Bp[8];
            short8 b3 = Bp[12];
            acc[nt] = __builtin_amdgcn_mfma_f32_16x16x32_bf16(a0, b0, acc[nt], 0, 0, 0);
            acc[nt] = __builtin_amdgcn_mfma_f32_16x16x32_bf16(a1, b1, acc[nt], 0, 0, 0);
            acc[nt] = __builtin_amdgcn_mfma_f32_16x16x32_bf16(a2, b2, acc[nt], 0, 0, 0);
            acc[nt] = __builtin_amdgcn_mfma_f32_16x16x32_bf16(a3, b3, acc[nt], 0, 0, 0);
        }
        __syncthreads();
        {
            int colBase = lane & 15;
            #pragma unroll
            for (int r = 0; r < 4; ++r) {
                int lr = wave * 16 + kg * 4 + r;
                #pragma unroll
                for (int nt = 0; nt < 8; ++nt)
                    sWT[lr * NFEAT + nt * 16 + colBase] = f2b(acc[nt][r]);
            }
        }
        __syncthreads();
        {
            int rowBase = gb * 128;
            const float4* sC4 = (const float4*)sWT;
            for (int i = t; i < 2048; i += 512) {
                int row = i >> 4;
                int gr = rowBase + row;
                if (gr < M) ((float4*)(C + (size_t)gr * NFEAT))[i & 15] = sC4[i];
            }
        }
    }
}

// ---------------- per-bucket ticketed counting sort -> CSR col + offsets + dinv ----------------
__global__ __launch_bounds__(256) void k_build(const uint32* __restrict__ bbuf, const int* __restrict__ cur,
                                               int* __restrict__ col, int* __restrict__ offsets,
                                               float* __restrict__ dinv) {
    int b = blockIdx.x;
    __shared__ int hist[BNODES], excl[BNODES];
    __shared__ int wsum[4], wtot[4];
    __shared__ int sorted[BCAP];              // 18 KB
    __shared__ int sBase, sTotal;
    int t = threadIdx.x;
    {
        int pre = 0, tot = 0;
        #pragma unroll
        for (int q = 0; q < 2; ++q) {
            int i = 2 * t + q;
            if (i < NBUCK) {
                int v = cur[i]; if (v > BCAP) v = BCAP;
                tot += v;
                if (i < b) pre += v;
            }
        }
        int lane = t & 63, w = t >> 6;
        #pragma unroll
        for (int d = 32; d > 0; d >>= 1) { pre += __shfl_down(pre, d, 64); tot += __shfl_down(tot, d, 64); }
        if (lane == 0) { wsum[w] = pre; wtot[w] = tot; }
        __syncthreads();
        if (t == 0) {
            sBase = wsum[0] + wsum[1] + wsum[2] + wsum[3];
            sTotal = wtot[0] + wtot[1] + wtot[2] + wtot[3];
        }
        hist[t] = 0;
    }
    __syncthreads();
    int base = sBase;
    if (b == NBUCK - 1 && t == 0) offsets[N_NODES] = sTotal;
    int cnt = cur[b]; if (cnt > BCAP) cnt = BCAP;
    const uint32* reg = bbuf + (size_t)b * BCAP;

    uint32 val[BD_EPT];
    int    meta[BD_EPT];   // (node << 16) | ticket
    #pragma unroll
    for (int k = 0; k < BD_EPT; ++k) {
        int i = t + k * 256;
        meta[k] = -1;
        if (i < cnt) {
            uint32 p = reg[i];
            int node = p >> 17;
            int tk = atomicAdd(&hist[node], 1);
            val[k] = p & 0x1FFFF;
            meta[k] = (node << 16) | tk;
        }
    }
    __syncthreads();
    {
        int c = hist[t];
        int lane = t & 63, w = t >> 6;
        int inc = c;
        #pragma unroll
        for (int d = 1; d < 64; d <<= 1) {
            int u = __shfl_up(inc, d, 64);
            if (lane >= d) inc += u;
        }
        if (lane == 63) wsum[w] = inc;
        __syncthreads();
        int wpre = 0;
        for (int i = 0; i < w; ++i) wpre += wsum[i];
        int e = wpre + inc - c;
        excl[t] = e;
        int node = (b << BSHIFT) + t;
        if (node < N_NODES) {
            offsets[node] = base + e;
            dinv[node] = rsqrtf((float)(c + 1));
        }
    }
    __syncthreads();
    #pragma unroll
    for (int k = 0; k < BD_EPT; ++k) {
        if (meta[k] >= 0) {
            int node = meta[k] >> 16;
            sorted[excl[node] + (meta[k] & 0xFFFF)] = (int)val[k];
        }
    }
    __syncthreads();
    for (int i = t; i < cnt; i += 256) col[base + i] = sorted[i];
}

// ---------------- aggregation core: 4 nodes per wave, 8-wide gather pipeline ----------------
#define AGG_GROUP4 \
    int half = lane >> 4; \
    int fl = lane & 15; \
    float dn = dinv[n]; \
    int e0 = off[n], e1 = off[n + 1]; \
    int deg = e1 - e0; \
    int maxd = deg; \
    { int u16 = __shfl_xor(maxd, 16, 64); if (u16 > maxd) maxd = u16; \
      int u32 = __shfl_xor(maxd, 32, 64); if (u32 > maxd) maxd = u32; } \
    const uint4* XW4 = (const uint4*)XWu; \
    uint4 sv = XW4[(size_t)n * 16 + fl]; \
    float ws = dn * dn; \
    float a0 = ws * blo(sv.x), a1 = ws * bhi(sv.x); \
    float a2 = ws * blo(sv.y), a3 = ws * bhi(sv.y); \
    float a4 = ws * blo(sv.z), a5 = ws * bhi(sv.z); \
    float a6 = ws * blo(sv.w), a7 = ws * bhi(sv.w); \
    int cm = 0; float wm = 0.f; \
    if (fl < deg) { cm = col[e0 + fl]; wm = dn * dinv[cm]; } \
    for (int base = 0; base < maxd; base += 16) { \
        int nb = base + 16; \
        int cmn = 0; float wmn = 0.f; \
        if (nb + fl < deg) { cmn = col[e0 + nb + fl]; wmn = dn * dinv[cmn]; } \
        int lim = maxd - base; if (lim > 16) lim = 16; \
        for (int j = 0; j < lim; j += 8) { \
            uint4 u[8]; float w[8]; \
            _Pragma("unroll") \
            for (int p = 0; p < 8; ++p) { \
                int sl = (half << 4) + j + p; \
                int cc = __shfl(cm, sl, 64); \
                w[p] = __shfl(wm, sl, 64); \
                u[p] = XW4[(size_t)cc * 16 + fl]; \
            } \
            _Pragma("unroll") \
            for (int p = 0; p < 8; ++p) { \
                a0 = fmaf(w[p], blo(u[p].x), a0); a1 = fmaf(w[p], bhi(u[p].x), a1); \
                a2 = fmaf(w[p], blo(u[p].y), a2); a3 = fmaf(w[p], bhi(u[p].y), a3); \
                a4 = fmaf(w[p], blo(u[p].z), a4); a5 = fmaf(w[p], bhi(u[p].z), a5); \
                a6 = fmaf(w[p], blo(u[p].w), a6); a7 = fmaf(w[p], bhi(u[p].w), a7); \
            } \
        } \
        cm = cmn; wm = wmn; \
    }

// ---------------- fused, per-wave, barrier-free: agg 4 nodes -> shuffle A-frag -> MFMA @ W ----------------
// Each wave owns 4 nodes (verified AGG_GROUP4 unchanged). The wave's H-tile [4][128] lives in
// registers (o, all 64 lanes); shuffles build the 16x32 MFMA A-fragments (rows 4..15 zero -> D
// rows 4..15 zero, ignored). B read from global WT (32 KB, L1/L2-hot). C staged through a
// 1 KB WAVE-PRIVATE LDS slot (wave-internal lgkmcnt only) -> coalesced 1 KB store.
// No __syncthreads anywhere: waves retire independently (kills the 4-wave barrier straggle).
__global__ __launch_bounds__(256) void k_agg_gemm(const uint32* __restrict__ XWu,
                                                  const int* __restrict__ col,
                                                  const int* __restrict__ off,
                                                  const float* __restrict__ dinv,
                                                  const float* __restrict__ bias,
                                                  const ushort* __restrict__ WTl,
                                                  ushort* __restrict__ C) {
    __shared__ __align__(16) ushort sC[4][4 * NFEAT];     // 4 waves x 1 KB, wave-private slots
    int t = threadIdx.x;
    int lane = t & 63;
    int lw = t >> 6;
    int wid = (blockIdx.x << 2) + lw;                     // 25000 waves, 4 nodes each
    int n = (wid << 2) + (lane >> 4);                     // 100000 = 25000*4 exactly, no tail
    AGG_GROUP4
    // bias + relu + pack: lane (half,fl) holds node half, features [fl*8, fl*8+8) as 4x bf16x2
    uint4 o;
    {
        float4 bb0 = ((const float4*)bias)[2 * fl];
        float4 bb1 = ((const float4*)bias)[2 * fl + 1];
        float r0 = fmaxf(a0 + bb0.x, 0.f), r1 = fmaxf(a1 + bb0.y, 0.f);
        float r2 = fmaxf(a2 + bb0.z, 0.f), r3 = fmaxf(a3 + bb0.w, 0.f);
        float r4 = fmaxf(a4 + bb1.x, 0.f), r5 = fmaxf(a5 + bb1.y, 0.f);
        float r6 = fmaxf(a6 + bb1.z, 0.f), r7 = fmaxf(a7 + bb1.w, 0.f);
        o.x = (uint32)f2b(r0) | ((uint32)f2b(r1) << 16);
        o.y = (uint32)f2b(r2) | ((uint32)f2b(r3) << 16);
        o.z = (uint32)f2b(r4) | ((uint32)f2b(r5) << 16);
        o.w = (uint32)f2b(r6) | ((uint32)f2b(r7) << 16);
    }
    // C4[4][128] = H4[4][128] @ W.  A-frag af_s: lane l = A[row=l&15][k=(l>>4)*8 + s*32];
    // source lane = (l&15)*16 + (l>>4) + s*4 (its o = that row's feature chunk). rows>=4 -> 0.
    int rowIdx = lane & 15;
    int kg = lane >> 4;
    f32x4 acc2[8];
    #pragma unroll
    for (int nt = 0; nt < 8; ++nt) acc2[nt] = (f32x4){0.f, 0.f, 0.f, 0.f};
    #pragma unroll
    for (int s = 0; s < 4; ++s) {
        int srcLane = rowIdx * 16 + kg + s * 4;
        union { int4 i; short8 h; } cvt;
        cvt.i.x = __shfl((int)o.x, srcLane, 64);
        cvt.i.y = __shfl((int)o.y, srcLane, 64);
        cvt.i.z = __shfl((int)o.z, srcLane, 64);
        cvt.i.w = __shfl((int)o.w, srcLane, 64);
        if (rowIdx >= 4) { cvt.i.x = 0; cvt.i.y = 0; cvt.i.z = 0; cvt.i.w = 0; }
        short8 af = cvt.h;
        #pragma unroll
        for (int nt = 0; nt < 8; ++nt) {
            short8 bf = *(const short8*)(WTl + (nt * 16 + rowIdx) * NFEAT + s * 32 + kg * 8);
            acc2[nt] = __builtin_amdgcn_mfma_f32_16x16x32_bf16(af, bf, acc2[nt], 0, 0, 0);
        }
    }
    // D layout: col = lane&15, row = (lane>>4)*4 + r -> real rows 0..3 live in lanes 0..15 (kg==0)
    if (kg == 0) {
        #pragma unroll
        for (int nt = 0; nt < 8; ++nt) {
            #pragma unroll
            for (int r = 0; r < 4; ++r)
                sC[lw][r * NFEAT + nt * 16 + rowIdx] = f2b(acc2[nt][r]);
        }
    }
    asm volatile("s_waitcnt lgkmcnt(0)" ::: "memory");
    __builtin_amdgcn_sched_barrier(0);
    {
        // row = kg (0..3), 16B chunk = rowIdx; 64 lanes -> 1 KB contiguous per wave
        uint4 v = *(const uint4*)&sC[lw][kg * NFEAT + rowIdx * 8];
        ((uint4*)(C + (size_t)((wid << 2) + kg) * NFEAT))[rowIdx] = v;
    }
}

__global__ __launch_bounds__(256) void k_agg_fc(const uint32* __restrict__ XWu, const int* __restrict__ col,
                                                const int* __restrict__ off, const float* __restrict__ dinv,
                                                const float* __restrict__ bias, const float* __restrict__ Wfc,
                                                float* __restrict__ nodeS) {
    int wid = (blockIdx.x * blockDim.x + threadIdx.x) >> 6;
    int lane = threadIdx.x & 63;
    int n = (wid << 2) + (lane >> 4);
    if (n >= N_NODES) return;
    AGG_GROUP4
    float4 bb0 = ((const float4*)bias)[2 * fl];
    float4 bb1 = ((const float4*)bias)[2 * fl + 1];
    float4 wf0 = ((const float4*)Wfc)[2 * fl];
    float4 wf1 = ((const float4*)Wfc)[2 * fl + 1];
    float s = fmaxf(a0 + bb0.x, 0.f) * wf0.x + fmaxf(a1 + bb0.y, 0.f) * wf0.y
            + fmaxf(a2 + bb0.z, 0.f) * wf0.z + fmaxf(a3 + bb0.w, 0.f) * wf0.w
            + fmaxf(a4 + bb1.x, 0.f) * wf1.x + fmaxf(a5 + bb1.y, 0.f) * wf1.y
            + fmaxf(a6 + bb1.z, 0.f) * wf1.z + fmaxf(a7 + bb1.w, 0.f) * wf1.w;
    // reduce within the 16-lane group (xor distances 8/4/2/1 stay inside the group)
    s += __shfl_xor(s, 8, 64);
    s += __shfl_xor(s, 4, 64);
    s += __shfl_xor(s, 2, 64);
    s += __shfl_xor(s, 1, 64);
    if (fl == 0) nodeS[n] = s;
}

// ---------------- segment mean over sorted batch + bias (one block per graph) ----------------
__device__ inline int lower_bound_dev(const int* a, int n, int key) {
    int lo = 0, hi = n;
    while (lo < hi) {
        int mid = (lo + hi) >> 1;
        if (a[mid] < key) lo = mid + 1; else hi = mid;
    }
    return lo;
}

__global__ __launch_bounds__(256) void k_pool(const float* __restrict__ nodeS, const int* __restrict__ batch,
                                              const float* __restrict__ bfc, float* __restrict__ out) {
    int g = blockIdx.x;
    int t = threadIdx.x;
    int lo = lower_bound_dev(batch, N_NODES, g);
    int hi = lower_bound_dev(batch, N_NODES, g + 1);
    float s = 0.f;
    for (int i = lo + t; i < hi; i += 256) s += nodeS[i];
    for (int d = 32; d > 0; d >>= 1) s += __shfl_down(s, d, 64);
    __shared__ float ws[4];
    int lane = t & 63, w = t >> 6;
    if (lane == 0) ws[w] = s;
    __syncthreads();
    if (t == 0) {
        float tot = ws[0] + ws[1] + ws[2] + ws[3];
        float cnt = (float)(hi - lo);
        out[g] = tot / fmaxf(cnt, 1.0f) + bfc[0];
    }
}

// ---------------- launch ----------------
extern "C" void kernel_launch(void* const* d_in, const int* in_sizes, int n_in,
                              void* d_out, int out_size, void* d_ws, size_t ws_size,
                              hipStream_t stream) {
    const float* x    = (const float*)d_in[0];
    const int*   ei   = (const int*)d_in[1];     // [2, E] : row0 = src, row1 = dst
    const int*   batch= (const int*)d_in[2];
    const float* W1   = (const float*)d_in[3];
    const float* b1   = (const float*)d_in[4];
    const float* W2   = (const float*)d_in[5];
    const float* b2   = (const float*)d_in[6];
    const float* W3   = (const float*)d_in[7];
    const float* b3   = (const float*)d_in[8];
    const float* Wfc  = (const float*)d_in[9];
    const float* bfc  = (const float*)d_in[10];
    float* out = (float*)d_out;

    const int* src = ei;
    const int* dst = ei + N_EDGES;

    // carve workspace (256B-aligned)
    char* p = (char*)d_ws;
    auto carve = [&](size_t bytes) { void* r = (void*)p; p += (bytes + 255) & ~(size_t)255; return r; };
    int*    cur       = (int*)   carve(sizeof(int) * NBUCK);
    uint32* bbuf      = (uint32*)carve(sizeof(uint32) * (size_t)NBUCK * BCAP);            // 7.2 MB
    float*  dinv      = (float*) carve(sizeof(float) * N_NODES);
    int*    offsets   = (int*)   carve(sizeof(int) * (N_NODES + 1));
    int*    col       = (int*)   carve(sizeof(int) * N_EDGES);
    ushort* XW        = (ushort*)carve(sizeof(short) * (size_t)N_NODES * NFEAT);
    ushort* XW2       = (ushort*)carve(sizeof(short) * (size_t)N_NODES * NFEAT);          // ping-pong
    ushort* WT        = (ushort*)carve(sizeof(short) * 3 * NFEAT * NFEAT);
    float*  nodeS     = (float*) carve(sizeof(float) * N_NODES);

    const int aggBlocks = N_NODES / 16;   // 6250 (4 waves/block x 4 nodes/wave)

    k_castw<<<(3 * NFEAT * NFEAT + 255) / 256, 256, 0, stream>>>(W1, W2, W3, WT, cur);
    // phase 1: scatter || layer-1 GEMM (independent work co-scheduled)  -> XW = x @ W1
    k_phase1<<<SC_BLOCKS + GEMM_BLOCKS, 512, 0, stream>>>(src, dst, cur, bbuf, x, WT, XW, N_NODES);
    k_build<<<NBUCK, 256, 0, stream>>>(bbuf, cur, col, offsets, dinv);

    // fused layer-1 agg + layer-2 GEMM:  XW2 = relu(A·XW + b1) @ W2
    k_agg_gemm<<<aggBlocks, 256, 0, stream>>>((const uint32*)XW, col, offsets, dinv, b1,
                                              WT + NFEAT * NFEAT, XW2);
    // fused layer-2 agg + layer-3 GEMM:  XW = relu(A·XW2 + b2) @ W3
    k_agg_gemm<<<aggBlocks, 256, 0, stream>>>((const uint32*)XW2, col, offsets, dinv, b2,
                                              WT + 2 * NFEAT * NFEAT, XW);
    // layer-3 agg + FC
    k_agg_fc<<<aggBlocks, 256, 0, stream>>>((const uint32*)XW, col, offsets, dinv, b3, Wfc, nodeS);

    k_pool<<<N_GRAPHS, 256, 0, stream>>>(nodeS, batch, bfc, out);
}

// Round 9
// 354.133 us; speedup vs baseline: 1.4716x; 1.4519x over previous
//
#include <hip/hip_runtime.h>

#define N_NODES   100000
#define N_EDGES   1600000
#define NFEAT     128
#define N_GRAPHS  1024

// ---- bucketed CSR build ----
#define BSHIFT  8
#define BNODES  256
#define NBUCK   391                  // ceil(100000 / 256)
#define BCAP    4608                 // mean 4096 + 8 sigma
#define SC_EDGES 4096
#define SC_EPT   8                   // edges per thread (4096/512)
#define SC_BLOCKS 391                // ceil(1.6M / 4096)
#define BD_EPT   18                  // ceil(BCAP/256)

#define WT_STRIDE 136
#define GEMM_BLOCKS 782              // ceil(100000/128)

typedef unsigned int uint32;
typedef unsigned short ushort;
typedef __attribute__((ext_vector_type(8))) short short8;   // 8 bf16 (4 VGPRs)
typedef __attribute__((ext_vector_type(4))) float f32x4;

// fp32 -> bf16 bits, round-to-nearest-even (finite inputs)
__device__ inline ushort f2b(float f) {
    uint32 x = __float_as_uint(f);
    uint32 r = x + 0x7fffu + ((x >> 16) & 1u);
    return (ushort)(r >> 16);
}
__device__ inline float blo(uint32 u) { return __uint_as_float(u << 16); }
__device__ inline float bhi(uint32 u) { return __uint_as_float(u & 0xffff0000u); }

__device__ inline short8 cvt8(const float* p) {
    float4 v0 = ((const float4*)p)[0];
    float4 v1 = ((const float4*)p)[1];
    short8 r;
    r[0] = (short)f2b(v0.x); r[1] = (short)f2b(v0.y);
    r[2] = (short)f2b(v0.z); r[3] = (short)f2b(v0.w);
    r[4] = (short)f2b(v1.x); r[5] = (short)f2b(v1.y);
    r[6] = (short)f2b(v1.z); r[7] = (short)f2b(v1.w);
    return r;
}

// ---------------- cast+transpose W -> WT bf16 [layer][n][k]; also zero cur ----------------
__global__ __launch_bounds__(256) void k_castw(const float* __restrict__ W1, const float* __restrict__ W2,
                                               const float* __restrict__ W3, ushort* __restrict__ WT,
                                               int* __restrict__ cur) {
    int i = blockIdx.x * blockDim.x + threadIdx.x;   // 3*16384
    if (i < NBUCK) cur[i] = 0;
    if (i >= 3 * NFEAT * NFEAT) return;
    int l = i >> 14;
    int j = i & 16383;
    int n = j >> 7;
    int k = j & 127;
    const float* W = (l == 0) ? W1 : (l == 1) ? W2 : W3;
    WT[i] = f2b(W[k * NFEAT + n]);   // WT[l][n*128+k] = W[k][n]
}

// ---------------- phase 1: scatter (blocks 0..390) || layer-1 GEMM (blocks 391..1172) ----------------
// Scatter de-staged: ticket count -> per-bucket global reservation -> DIRECT scattered write.
// Same-bucket tickets within a block are consecutive slots (~10/bucket), so L2 coalesces the
// scattered stores; drops the 24KB LDS staging, the 256-thread scan, and 2 barriers.
struct SMemScatter {
    int hist[NBUCK], gbase[NBUCK];
};

__global__ __launch_bounds__(512) void k_phase1(const int* __restrict__ src, const int* __restrict__ dst,
                                                int* __restrict__ cur, uint32* __restrict__ bbuf,
                                                const float* __restrict__ A, const ushort* __restrict__ WTl,
                                                ushort* __restrict__ C, int M) {
    __shared__ __align__(16) char smem[NFEAT * WT_STRIDE * 2];   // 34 KB (GEMM branch needs it)
    int t = threadIdx.x;
    if (blockIdx.x < SC_BLOCKS) {
        SMemScatter& S = *(SMemScatter*)smem;
        int e0 = blockIdx.x * SC_EDGES;
        int total = N_EDGES - e0; if (total > SC_EDGES) total = SC_EDGES; if (total < 0) total = 0;
        for (int i = t; i < NBUCK; i += 512) S.hist[i] = 0;
        __syncthreads();
        uint32 val[SC_EPT];
        int    meta[SC_EPT];    // (bucket << 13) | ticket
        #pragma unroll
        for (int k = 0; k < SC_EPT; ++k) {
            int i = t + k * 512;
            meta[k] = -1;
            if (i < total) {
                int s = src[e0 + i], d = dst[e0 + i];
                int b = d >> BSHIFT;
                int tk = atomicAdd(&S.hist[b], 1);
                val[k] = ((uint32)(d & (BNODES - 1)) << 17) | (uint32)s;
                meta[k] = (b << 13) | tk;
            }
        }
        __syncthreads();
        for (int i = t; i < NBUCK; i += 512) {
            int h = S.hist[i];
            if (h) S.gbase[i] = atomicAdd(&cur[i], h);
        }
        __syncthreads();
        #pragma unroll
        for (int k = 0; k < SC_EPT; ++k) {
            if (meta[k] >= 0) {
                int b = meta[k] >> 13;
                int addr = S.gbase[b] + (meta[k] & 0x1FFF);
                if (addr < BCAP)
                    bbuf[(size_t)b * BCAP + addr] = val[k];
            }
        }
    } else {
        // ================== layer-1 GEMM (fp32 A, cast fused) ==================
        ushort* sWT = (ushort*)smem;
        int gb = blockIdx.x - SC_BLOCKS;
        for (int i = t; i < NFEAT * 16; i += 512) {
            int n = i >> 4, c = i & 15;
            *(float4*)(sWT + n * WT_STRIDE + c * 8) = ((const float4*)WTl)[i];
        }
        int wave = t >> 6, lane = t & 63;
        int m0 = gb * 128 + wave * 16;
        int mRow = m0 + (lane & 15);
        if (mRow >= M) mRow = M - 1;
        int kg = lane >> 4;
        const float* Ap = A + (size_t)mRow * NFEAT + kg * 8;
        short8 a0 = cvt8(Ap);
        short8 a1 = cvt8(Ap + 32);
        short8 a2 = cvt8(Ap + 64);
        short8 a3 = cvt8(Ap + 96);
        __syncthreads();

        f32x4 acc[8];
        #pragma unroll
        for (int nt = 0; nt < 8; ++nt) acc[nt] = (f32x4){0.f, 0.f, 0.f, 0.f};
        #pragma unroll
        for (int nt = 0; nt < 8; ++nt) {
            int n = nt * 16 + (lane & 15);
            const short8* Bp = (const short8*)(sWT + n * WT_STRIDE + kg * 8);
            short8 b0 = Bp[0];
            short8 b1 = Bp[4];
            short8 b2 = Bp[8];
            short8 b3 = Bp[12];
            acc[nt] = __builtin_amdgcn_mfma_f32_16x16x32_bf16(a0, b0, acc[nt], 0, 0, 0);
            acc[nt] = __builtin_amdgcn_mfma_f32_16x16x32_bf16(a1, b1, acc[nt], 0, 0, 0);
            acc[nt] = __builtin_amdgcn_mfma_f32_16x16x32_bf16(a2, b2, acc[nt], 0, 0, 0);
            acc[nt] = __builtin_amdgcn_mfma_f32_16x16x32_bf16(a3, b3, acc[nt], 0, 0, 0);
        }
        __syncthreads();
        {
            int colBase = lane & 15;
            #pragma unroll
            for (int r = 0; r < 4; ++r) {
                int lr = wave * 16 + kg * 4 + r;
                #pragma unroll
                for (int nt = 0; nt < 8; ++nt)
                    sWT[lr * NFEAT + nt * 16 + colBase] = f2b(acc[nt][r]);
            }
        }
        __syncthreads();
        {
            int rowBase = gb * 128;
            const float4* sC4 = (const float4*)sWT;
            for (int i = t; i < 2048; i += 512) {
                int row = i >> 4;
                int gr = rowBase + row;
                if (gr < M) ((float4*)(C + (size_t)gr * NFEAT))[i & 15] = sC4[i];
            }
        }
    }
}

// ---------------- per-bucket ticketed counting sort -> CSR col + offsets + dinv ----------------
// De-staged: ticket count -> hist scan (still needed for offsets) -> DIRECT col write.
// Drops the 18KB sorted[] staging and the final coalescing pass; LDS 2.5 KB.
__global__ __launch_bounds__(256) void k_build(const uint32* __restrict__ bbuf, const int* __restrict__ cur,
                                               int* __restrict__ col, int* __restrict__ offsets,
                                               float* __restrict__ dinv) {
    int b = blockIdx.x;
    __shared__ int hist[BNODES], excl[BNODES];
    __shared__ int wsum[4], wtot[4];
    __shared__ int sBase, sTotal;
    int t = threadIdx.x;
    {
        int pre = 0, tot = 0;
        #pragma unroll
        for (int q = 0; q < 2; ++q) {
            int i = 2 * t + q;
            if (i < NBUCK) {
                int v = cur[i]; if (v > BCAP) v = BCAP;
                tot += v;
                if (i < b) pre += v;
            }
        }
        int lane = t & 63, w = t >> 6;
        #pragma unroll
        for (int d = 32; d > 0; d >>= 1) { pre += __shfl_down(pre, d, 64); tot += __shfl_down(tot, d, 64); }
        if (lane == 0) { wsum[w] = pre; wtot[w] = tot; }
        __syncthreads();
        if (t == 0) {
            sBase = wsum[0] + wsum[1] + wsum[2] + wsum[3];
            sTotal = wtot[0] + wtot[1] + wtot[2] + wtot[3];
        }
        hist[t] = 0;
    }
    __syncthreads();
    int base = sBase;
    if (b == NBUCK - 1 && t == 0) offsets[N_NODES] = sTotal;
    int cnt = cur[b]; if (cnt > BCAP) cnt = BCAP;
    const uint32* reg = bbuf + (size_t)b * BCAP;

    uint32 val[BD_EPT];
    int    meta[BD_EPT];   // (node << 16) | ticket
    #pragma unroll
    for (int k = 0; k < BD_EPT; ++k) {
        int i = t + k * 256;
        meta[k] = -1;
        if (i < cnt) {
            uint32 p = reg[i];
            int node = p >> 17;
            int tk = atomicAdd(&hist[node], 1);
            val[k] = p & 0x1FFFF;
            meta[k] = (node << 16) | tk;
        }
    }
    __syncthreads();
    {
        int c = hist[t];
        int lane = t & 63, w = t >> 6;
        int inc = c;
        #pragma unroll
        for (int d = 1; d < 64; d <<= 1) {
            int u = __shfl_up(inc, d, 64);
            if (lane >= d) inc += u;
        }
        if (lane == 63) wsum[w] = inc;
        __syncthreads();
        int wpre = 0;
        for (int i = 0; i < w; ++i) wpre += wsum[i];
        int e = wpre + inc - c;
        excl[t] = e;
        int node = (b << BSHIFT) + t;
        if (node < N_NODES) {
            offsets[node] = base + e;
            dinv[node] = rsqrtf((float)(c + 1));
        }
    }
    __syncthreads();
    #pragma unroll
    for (int k = 0; k < BD_EPT; ++k) {
        if (meta[k] >= 0) {
            int node = meta[k] >> 16;
            col[base + excl[node] + (meta[k] & 0xFFFF)] = (int)val[k];
        }
    }
}

// ---------------- aggregation core: 4 nodes per wave, 8-wide gather pipeline ----------------
#define AGG_GROUP4 \
    int half = lane >> 4; \
    int fl = lane & 15; \
    float dn = dinv[n]; \
    int e0 = off[n], e1 = off[n + 1]; \
    int deg = e1 - e0; \
    int maxd = deg; \
    { int u16 = __shfl_xor(maxd, 16, 64); if (u16 > maxd) maxd = u16; \
      int u32 = __shfl_xor(maxd, 32, 64); if (u32 > maxd) maxd = u32; } \
    const uint4* XW4 = (const uint4*)XWu; \
    uint4 sv = XW4[(size_t)n * 16 + fl]; \
    float ws = dn * dn; \
    float a0 = ws * blo(sv.x), a1 = ws * bhi(sv.x); \
    float a2 = ws * blo(sv.y), a3 = ws * bhi(sv.y); \
    float a4 = ws * blo(sv.z), a5 = ws * bhi(sv.z); \
    float a6 = ws * blo(sv.w), a7 = ws * bhi(sv.w); \
    int cm = 0; float wm = 0.f; \
    if (fl < deg) { cm = col[e0 + fl]; wm = dn * dinv[cm]; } \
    for (int base = 0; base < maxd; base += 16) { \
        int nb = base + 16; \
        int cmn = 0; float wmn = 0.f; \
        if (nb + fl < deg) { cmn = col[e0 + nb + fl]; wmn = dn * dinv[cmn]; } \
        int lim = maxd - base; if (lim > 16) lim = 16; \
        for (int j = 0; j < lim; j += 8) { \
            uint4 u[8]; float w[8]; \
            _Pragma("unroll") \
            for (int p = 0; p < 8; ++p) { \
                int sl = (half << 4) + j + p; \
                int cc = __shfl(cm, sl, 64); \
                w[p] = __shfl(wm, sl, 64); \
                u[p] = XW4[(size_t)cc * 16 + fl]; \
            } \
            _Pragma("unroll") \
            for (int p = 0; p < 8; ++p) { \
                a0 = fmaf(w[p], blo(u[p].x), a0); a1 = fmaf(w[p], bhi(u[p].x), a1); \
                a2 = fmaf(w[p], blo(u[p].y), a2); a3 = fmaf(w[p], bhi(u[p].y), a3); \
                a4 = fmaf(w[p], blo(u[p].z), a4); a5 = fmaf(w[p], bhi(u[p].z), a5); \
                a6 = fmaf(w[p], blo(u[p].w), a6); a7 = fmaf(w[p], bhi(u[p].w), a7); \
            } \
        } \
        cm = cmn; wm = wmn; \
    }

// ---------------- fused: agg(+bias,relu) 16 nodes/block -> 4.3KB LDS A-tile -> MFMA @ W ----------------
// R5-verified block-tile epilogue: accumulators live only AFTER the gather (register pressure
// stays out of the gather's live range — R7 showed the per-wave variant breaks the pipeline).
__global__ __launch_bounds__(256) void k_agg_gemm(const uint32* __restrict__ XWu,
                                                  const int* __restrict__ col,
                                                  const int* __restrict__ off,
                                                  const float* __restrict__ dinv,
                                                  const float* __restrict__ bias,
                                                  const ushort* __restrict__ WTl,
                                                  ushort* __restrict__ C) {
    __shared__ __align__(16) ushort sA[16 * WT_STRIDE];   // 4.25 KB (A-tile, reused for C staging)
    int t = threadIdx.x;
    int lane = t & 63;
    int lw = t >> 6;                                      // wave 0..3
    int n = (blockIdx.x << 4) + (lw << 2) + (lane >> 4);  // N_NODES = 6250*16 exactly, no tail
    AGG_GROUP4
    // bias + relu + pack to bf16, stage row into LDS
    {
        float4 bb0 = ((const float4*)bias)[2 * fl];
        float4 bb1 = ((const float4*)bias)[2 * fl + 1];
        float r0 = fmaxf(a0 + bb0.x, 0.f), r1 = fmaxf(a1 + bb0.y, 0.f);
        float r2 = fmaxf(a2 + bb0.z, 0.f), r3 = fmaxf(a3 + bb0.w, 0.f);
        float r4 = fmaxf(a4 + bb1.x, 0.f), r5 = fmaxf(a5 + bb1.y, 0.f);
        float r6 = fmaxf(a6 + bb1.z, 0.f), r7 = fmaxf(a7 + bb1.w, 0.f);
        uint4 o;
        o.x = (uint32)f2b(r0) | ((uint32)f2b(r1) << 16);
        o.y = (uint32)f2b(r2) | ((uint32)f2b(r3) << 16);
        o.z = (uint32)f2b(r4) | ((uint32)f2b(r5) << 16);
        o.w = (uint32)f2b(r6) | ((uint32)f2b(r7) << 16);
        int lrow = (lw << 2) + half;                      // local node 0..15
        *(uint4*)(sA + lrow * WT_STRIDE + fl * 8) = o;
    }
    __syncthreads();
    // GEMM epilogue: wave lw computes column-tiles nt = 2lw, 2lw+1 of C[16,128]
    {
        const short8* Ap = (const short8*)(sA + fl * WT_STRIDE + half * 8);
        short8 af0 = Ap[0];
        short8 af1 = Ap[4];
        short8 af2 = Ap[8];
        short8 af3 = Ap[12];
        f32x4 acc[2];
        acc[0] = (f32x4){0.f, 0.f, 0.f, 0.f};
        acc[1] = (f32x4){0.f, 0.f, 0.f, 0.f};
        #pragma unroll
        for (int q = 0; q < 2; ++q) {
            int nt = lw * 2 + q;
            const short8* Bp = (const short8*)(WTl + (nt * 16 + fl) * NFEAT + half * 8);
            short8 b0 = Bp[0];
            short8 b1 = Bp[4];
            short8 b2 = Bp[8];
            short8 b3 = Bp[12];
            acc[q] = __builtin_amdgcn_mfma_f32_16x16x32_bf16(af0, b0, acc[q], 0, 0, 0);
            acc[q] = __builtin_amdgcn_mfma_f32_16x16x32_bf16(af1, b1, acc[q], 0, 0, 0);
            acc[q] = __builtin_amdgcn_mfma_f32_16x16x32_bf16(af2, b2, acc[q], 0, 0, 0);
            acc[q] = __builtin_amdgcn_mfma_f32_16x16x32_bf16(af3, b3, acc[q], 0, 0, 0);
        }
        __syncthreads();
        // C/D layout: col = lane&15 (fl), row = (lane>>4)*4 + r (half*4+r)
        #pragma unroll
        for (int q = 0; q < 2; ++q) {
            int nt = lw * 2 + q;
            #pragma unroll
            for (int r = 0; r < 4; ++r)
                sA[(half * 4 + r) * NFEAT + nt * 16 + fl] = f2b(acc[q][r]);
        }
    }
    __syncthreads();
    {
        int row = t >> 4;                                 // 0..15
        float4 v = ((const float4*)sA)[t];                // 256 float4 = 16 rows x 128 ushort
        ((float4*)(C + (size_t)((blockIdx.x << 4) + row) * NFEAT))[t & 15] = v;
    }
}

__global__ __launch_bounds__(256) void k_agg_fc(const uint32* __restrict__ XWu, const int* __restrict__ col,
                                                const int* __restrict__ off, const float* __restrict__ dinv,
                                                const float* __restrict__ bias, const float* __restrict__ Wfc,
                                                float* __restrict__ nodeS) {
    int wid = (blockIdx.x * blockDim.x + threadIdx.x) >> 6;
    int lane = threadIdx.x & 63;
    int n = (wid << 2) + (lane >> 4);
    if (n >= N_NODES) return;
    AGG_GROUP4
    float4 bb0 = ((const float4*)bias)[2 * fl];
    float4 bb1 = ((const float4*)bias)[2 * fl + 1];
    float4 wf0 = ((const float4*)Wfc)[2 * fl];
    float4 wf1 = ((const float4*)Wfc)[2 * fl + 1];
    float s = fmaxf(a0 + bb0.x, 0.f) * wf0.x + fmaxf(a1 + bb0.y, 0.f) * wf0.y
            + fmaxf(a2 + bb0.z, 0.f) * wf0.z + fmaxf(a3 + bb0.w, 0.f) * wf0.w
            + fmaxf(a4 + bb1.x, 0.f) * wf1.x + fmaxf(a5 + bb1.y, 0.f) * wf1.y
            + fmaxf(a6 + bb1.z, 0.f) * wf1.z + fmaxf(a7 + bb1.w, 0.f) * wf1.w;
    // reduce within the 16-lane group (xor distances 8/4/2/1 stay inside the group)
    s += __shfl_xor(s, 8, 64);
    s += __shfl_xor(s, 4, 64);
    s += __shfl_xor(s, 2, 64);
    s += __shfl_xor(s, 1, 64);
    if (fl == 0) nodeS[n] = s;
}

// ---------------- segment mean over sorted batch + bias (one block per graph) ----------------
__device__ inline int lower_bound_dev(const int* a, int n, int key) {
    int lo = 0, hi = n;
    while (lo < hi) {
        int mid = (lo + hi) >> 1;
        if (a[mid] < key) lo = mid + 1; else hi = mid;
    }
    return lo;
}

__global__ __launch_bounds__(256) void k_pool(const float* __restrict__ nodeS, const int* __restrict__ batch,
                                              const float* __restrict__ bfc, float* __restrict__ out) {
    int g = blockIdx.x;
    int t = threadIdx.x;
    int lo = lower_bound_dev(batch, N_NODES, g);
    int hi = lower_bound_dev(batch, N_NODES, g + 1);
    float s = 0.f;
    for (int i = lo + t; i < hi; i += 256) s += nodeS[i];
    for (int d = 32; d > 0; d >>= 1) s += __shfl_down(s, d, 64);
    __shared__ float ws[4];
    int lane = t & 63, w = t >> 6;
    if (lane == 0) ws[w] = s;
    __syncthreads();
    if (t == 0) {
        float tot = ws[0] + ws[1] + ws[2] + ws[3];
        float cnt = (float)(hi - lo);
        out[g] = tot / fmaxf(cnt, 1.0f) + bfc[0];
    }
}

// ---------------- launch ----------------
extern "C" void kernel_launch(void* const* d_in, const int* in_sizes, int n_in,
                              void* d_out, int out_size, void* d_ws, size_t ws_size,
                              hipStream_t stream) {
    const float* x    = (const float*)d_in[0];
    const int*   ei   = (const int*)d_in[1];     // [2, E] : row0 = src, row1 = dst
    const int*   batch= (const int*)d_in[2];
    const float* W1   = (const float*)d_in[3];
    const float* b1   = (const float*)d_in[4];
    const float* W2   = (const float*)d_in[5];
    const float* b2   = (const float*)d_in[6];
    const float* W3   = (const float*)d_in[7];
    const float* b3   = (const float*)d_in[8];
    const float* Wfc  = (const float*)d_in[9];
    const float* bfc  = (const float*)d_in[10];
    float* out = (float*)d_out;

    const int* src = ei;
    const int* dst = ei + N_EDGES;

    // carve workspace (256B-aligned)
    char* p = (char*)d_ws;
    auto carve = [&](size_t bytes) { void* r = (void*)p; p += (bytes + 255) & ~(size_t)255; return r; };
    int*    cur       = (int*)   carve(sizeof(int) * NBUCK);
    uint32* bbuf      = (uint32*)carve(sizeof(uint32) * (size_t)NBUCK * BCAP);            // 7.2 MB
    float*  dinv      = (float*) carve(sizeof(float) * N_NODES);
    int*    offsets   = (int*)   carve(sizeof(int) * (N_NODES + 1));
    int*    col       = (int*)   carve(sizeof(int) * N_EDGES);
    ushort* XW        = (ushort*)carve(sizeof(short) * (size_t)N_NODES * NFEAT);
    ushort* XW2       = (ushort*)carve(sizeof(short) * (size_t)N_NODES * NFEAT);          // ping-pong
    ushort* WT        = (ushort*)carve(sizeof(short) * 3 * NFEAT * NFEAT);
    float*  nodeS     = (float*) carve(sizeof(float) * N_NODES);

    const int aggBlocks = N_NODES / 16;   // 6250 exactly (100000 = 6250*16)

    k_castw<<<(3 * NFEAT * NFEAT + 255) / 256, 256, 0, stream>>>(W1, W2, W3, WT, cur);
    // phase 1: scatter || layer-1 GEMM (independent work co-scheduled)  -> XW = x @ W1
    k_phase1<<<SC_BLOCKS + GEMM_BLOCKS, 512, 0, stream>>>(src, dst, cur, bbuf, x, WT, XW, N_NODES);
    k_build<<<NBUCK, 256, 0, stream>>>(bbuf, cur, col, offsets, dinv);

    // fused layer-1 agg + layer-2 GEMM:  XW2 = relu(A·XW + b1) @ W2
    k_agg_gemm<<<aggBlocks, 256, 0, stream>>>((const uint32*)XW, col, offsets, dinv, b1,
                                              WT + NFEAT * NFEAT, XW2);
    // fused layer-2 agg + layer-3 GEMM:  XW = relu(A·XW2 + b2) @ W3
    k_agg_gemm<<<aggBlocks, 256, 0, stream>>>((const uint32*)XW2, col, offsets, dinv, b2,
                                              WT + 2 * NFEAT * NFEAT, XW);
    // layer-3 agg + FC
    k_agg_fc<<<aggBlocks, 256, 0, stream>>>((const uint32*)XW, col, offsets, dinv, b3, Wfc, nodeS);

    k_pool<<<N_GRAPHS, 256, 0, stream>>>(nodeS, batch, bfc, out);
}